// Round 1
// baseline (1269.862 us; speedup 1.0000x reference)
//
#include <hip/hip_runtime.h>

typedef _Float16 f16;
typedef _Float16 f16x8 __attribute__((ext_vector_type(8)));
typedef float f32x4 __attribute__((ext_vector_type(4)));

__device__ __forceinline__ float sigf(float x){ return 1.f/(1.f + __expf(-x)); }
__device__ __forceinline__ float tanhfast(float x){ return 2.f/(1.f + __expf(-2.f*x)) - 1.f; }

// ---------------- weight prep kernels (Bpack layout: [k>>3][n][k&7]) ----------------
__global__ void prep_w1(const float* __restrict__ w, f16* __restrict__ dst){
  int idx = blockIdx.x*256 + threadIdx.x;            // 32*4*8*8 = 8192
  if (idx >= 8192) return;
  int och = idx >> 8, rem = idx & 255;
  int c = rem >> 6, ky = (rem >> 3) & 7, kx = rem & 7;
  int k = (ky*8 + kx)*4 + c;                          // K-order (ky,kx,c), K=256
  dst[(k>>3)*256 + och*8 + (k&7)] = (f16)(w[idx] * (1.f/255.f));  // fold x/255
}
__global__ void prep_w2(const float* __restrict__ w, f16* __restrict__ dst){
  int idx = blockIdx.x*256 + threadIdx.x;            // 64*32*4*4 = 32768
  if (idx >= 32768) return;
  int och = idx >> 9;
  int c = (idx >> 4) & 31, ky = (idx >> 2) & 3, kx = idx & 3;
  int k = (ky*4 + kx)*32 + c;                         // K=512
  dst[(k>>3)*512 + och*8 + (k&7)] = (f16)w[idx];
}
__global__ void prep_w3(const float* __restrict__ w, f16* __restrict__ dst){
  int idx = blockIdx.x*256 + threadIdx.x;            // 64*64*3*3 = 36864
  if (idx >= 36864) return;
  int och = idx / 576, r = idx % 576;
  int c = r / 9, r2 = r % 9;
  int ky = r2 / 3, kx = r2 % 3;
  int k = (ky*3 + kx)*64 + c;                         // K=576
  dst[(k>>3)*512 + och*8 + (k&7)] = (f16)w[idx];
}
__global__ void prep_wf(const float* __restrict__ w, f16* __restrict__ dst){
  int idx = blockIdx.x*256 + threadIdx.x;            // 512*3136
  if (idx >= 512*3136) return;
  int n = idx / 3136, col = idx % 3136;
  int c = col / 49, r2 = col % 49;
  int iy = r2 / 7, ix = r2 % 7;
  int kf = (iy*7 + ix)*64 + c;                        // permute to channels-last flatten
  dst[(size_t)(kf>>3)*4096 + n*8 + (kf&7)] = (f16)w[idx];
}
__global__ void prep_wih(const float* __restrict__ w, f16* __restrict__ dst){
  int idx = blockIdx.x*256 + threadIdx.x;            // 512*512
  if (idx >= 512*512) return;
  int n = idx >> 9, k = idx & 511;
  dst[(size_t)(k>>3)*4096 + n*8 + (k&7)] = (f16)w[idx];
}
__global__ void prep_wheads(const float* __restrict__ wa, const float* __restrict__ wc,
                            f16* __restrict__ dst){
  int idx = blockIdx.x*256 + threadIdx.x;            // 32*128 (pad N 19->32)
  if (idx >= 4096) return;
  int n = idx >> 7, k = idx & 127;
  float v = 0.f;
  if (n < 18) v = wa[n*128 + k];
  else if (n == 18) v = wc[k];
  dst[(k>>3)*256 + n*8 + (k&7)] = (f16)v;
}
__global__ void prep_bsum(const float* __restrict__ a, const float* __restrict__ b,
                          float* __restrict__ s){
  int i = blockIdx.x*256 + threadIdx.x;
  if (i < 512) s[i] = a[i] + b[i];
}

// ---------------- conv1: (TB,4,84,84) -> (TB,20,20,32) channels-last fp16 ----------------
// implicit GEMM, M-block = 80 px (4 oy rows), N=32, K=256. A-frags b128 direct from raw tile.
__global__ __launch_bounds__(128) void conv1_k(const float* __restrict__ x,
    const f16* __restrict__ Bp, const float* __restrict__ b1, f16* __restrict__ y1){
  __shared__ alignas(16) f16 tile[20*84*4];          // [iy][ix][c] 13.4 KB
  int n = blockIdx.y, by = blockIdx.x;               // by in [0,5)
  const float* xn = x + (size_t)n*4*84*84;
  int iy0 = by*16;
  for (int i = threadIdx.x; i < 6720; i += 128){
    int c = i / 1680, r = i % 1680;
    int iy = r / 84, ix = r % 84;
    tile[(iy*84 + ix)*4 + c] = (f16)xn[(c*84 + iy0 + iy)*84 + ix];
  }
  int lane = threadIdx.x & 63, w = threadIdx.x >> 6;
  int q = lane >> 4, m = lane & 15;
  int och = w*16 + m;
  f16x8 bfr[8];
  #pragma unroll
  for (int s = 0; s < 8; ++s)
    bfr[s] = *(const f16x8*)(Bp + ((4*s + q)*32 + och)*8);
  __syncthreads();
  f32x4 acc[5] = {};
  #pragma unroll
  for (int mt = 0; mt < 5; ++mt){
    int px = mt*16 + m;
    int oy = px / 20, ox = px % 20;
    int base = oy*4*84 + ox*4;
    #pragma unroll
    for (int s = 0; s < 8; ++s){
      int k8 = 4*s + q;
      int ky = k8 >> 2, kx0 = (k8 & 3)*2;
      f16x8 a = *(const f16x8*)(&tile[(base + ky*84 + kx0)*4]);
      acc[mt] = __builtin_amdgcn_mfma_f32_16x16x32_f16(a, bfr[s], acc[mt], 0, 0, 0);
    }
  }
  float bias = b1[och];
  size_t obase = (size_t)n*400 + by*80;
  #pragma unroll
  for (int mt = 0; mt < 5; ++mt)
    #pragma unroll
    for (int r = 0; r < 4; ++r){
      int px = mt*16 + q*4 + r;
      float v = acc[mt][r] + bias; v = v > 0.f ? v : 0.f;
      y1[(obase + px)*32 + och] = (f16)v;
    }
}

// ---------------- conv2: (TB,20,20,32) -> (TB,9,9,64), K=512 ----------------
__global__ __launch_bounds__(256) void conv2_k(const f16* __restrict__ y1,
    const f16* __restrict__ Bp, const float* __restrict__ b2, f16* __restrict__ y2){
  __shared__ alignas(16) f16 tile[400*32];           // full y1 frame 25.6 KB
  int n = blockIdx.y, half = blockIdx.x;
  const f16* y1n = y1 + (size_t)n*12800;
  for (int i = threadIdx.x; i < 1600; i += 256)
    ((uint4*)tile)[i] = ((const uint4*)y1n)[i];
  int lane = threadIdx.x & 63, w = threadIdx.x >> 6;
  int q = lane >> 4, m = lane & 15;
  int mg = w >> 1, nt = w & 1;
  int och = half*32 + nt*16 + m;
  f16x8 bfr[16];
  #pragma unroll
  for (int s = 0; s < 16; ++s)
    bfr[s] = *(const f16x8*)(Bp + ((size_t)(4*s + q)*64 + och)*8);
  int basev[3];
  #pragma unroll
  for (int i = 0; i < 3; ++i){
    int px = (mg*3 + i)*16 + m;
    if (px > 80) px = 80;                            // pad rows clamp (stores guarded)
    int oy = px/9, ox = px%9;
    basev[i] = (oy*2)*20 + ox*2;
  }
  __syncthreads();
  f32x4 acc[3] = {};
  #pragma unroll
  for (int s = 0; s < 16; ++s){
    int k8 = 4*s + q;
    int c0 = (k8 & 3)*8;
    int kk = k8 >> 2;
    int off = ((kk >> 2)*20 + (kk & 3))*32 + c0;     // (ky*20+kx)*32+c0
    #pragma unroll
    for (int i = 0; i < 3; ++i){
      f16x8 a = *(const f16x8*)(&tile[basev[i]*32 + off]);
      acc[i] = __builtin_amdgcn_mfma_f32_16x16x32_f16(a, bfr[s], acc[i], 0, 0, 0);
    }
  }
  float bias = b2[och];
  #pragma unroll
  for (int i = 0; i < 3; ++i)
    #pragma unroll
    for (int r = 0; r < 4; ++r){
      int px = (mg*3 + i)*16 + q*4 + r;
      if (px < 81){
        float v = acc[i][r] + bias; v = v > 0.f ? v : 0.f;
        y2[((size_t)n*81 + px)*64 + och] = (f16)v;
      }
    }
}

// ---------------- conv3: (TB,9,9,64) -> (TB,49*64) flat channels-last, K=576 ----------------
__global__ __launch_bounds__(256) void conv3_k(const f16* __restrict__ y2,
    const f16* __restrict__ Bp, const float* __restrict__ b3, f16* __restrict__ y3){
  __shared__ alignas(16) f16 tile[81*64];            // 10.4 KB
  int n = blockIdx.x;
  const f16* y2n = y2 + (size_t)n*5184;
  for (int i = threadIdx.x; i < 648; i += 256)
    ((uint4*)tile)[i] = ((const uint4*)y2n)[i];
  int lane = threadIdx.x & 63, w = threadIdx.x >> 6;
  int q = lane >> 4, m = lane & 15;
  int och = w*16 + m;
  int basev[4];
  #pragma unroll
  for (int i = 0; i < 4; ++i){
    int px = i*16 + m; if (px > 48) px = 48;
    basev[i] = (px/7)*9 + (px%7);
  }
  __syncthreads();
  f32x4 acc[4] = {};
  for (int s = 0; s < 18; ++s){
    int k8 = 4*s + q;
    int c0 = (k8 & 7)*8;
    int kxy = k8 >> 3;                               // 0..8
    int ky = kxy/3, kx = kxy%3;
    f16x8 b = *(const f16x8*)(Bp + ((size_t)k8*64 + och)*8);
    int off = (ky*9 + kx)*64 + c0;
    #pragma unroll
    for (int i = 0; i < 4; ++i){
      f16x8 a = *(const f16x8*)(&tile[basev[i]*64 + off]);
      acc[i] = __builtin_amdgcn_mfma_f32_16x16x32_f16(a, b, acc[i], 0, 0, 0);
    }
  }
  float bias = b3[och];
  #pragma unroll
  for (int i = 0; i < 4; ++i)
    #pragma unroll
    for (int r = 0; r < 4; ++r){
      int px = i*16 + q*4 + r;
      if (px < 49)
        {
          float v = acc[i][r] + bias; v = v > 0.f ? v : 0.f;
          y3[((size_t)n*49 + px)*64 + och] = (f16)v;
        }
    }
}

// ---------------- generic GEMM: out(M,N) = A(M,K)fp16 @ Bpack + bias ----------------
template<bool RELU, bool OUTH>
__global__ __launch_bounds__(256) void gemm_k(const f16* __restrict__ A,
    const f16* __restrict__ Bp, const float* __restrict__ bias, void* __restrict__ out,
    int M, int N, int K){
  __shared__ alignas(16) f16 at[64*264];             // 64 rows, K_BLK=256 (+8 pad)
  int m0 = blockIdx.x*64, n0 = blockIdx.y*64;
  int lane = threadIdx.x & 63, w = threadIdx.x >> 6;
  int q = lane >> 4, cl = lane & 15;
  int mh = w >> 1, nh = w & 1;
  f32x4 acc[2][2] = {};
  for (int kb = 0; kb < K; kb += 256){
    int kblen = K - kb; if (kblen > 256) kblen = 256;
    int c8n = kblen >> 3;
    __syncthreads();
    int tot = 64*c8n;
    for (int i = threadIdx.x; i < tot; i += 256){
      int row, c8;
      if (c8n == 32){ row = i >> 5; c8 = i & 31; } else { row = i >> 3; c8 = i & 7; }
      *(f16x8*)(&at[row*264 + c8*8]) = *(const f16x8*)(&A[(size_t)(m0+row)*K + kb + c8*8]);
    }
    __syncthreads();
    int nks = kblen >> 5;
    for (int s = 0; s < nks; ++s){
      f16x8 a[2], b[2];
      #pragma unroll
      for (int mi = 0; mi < 2; ++mi)
        a[mi] = *(const f16x8*)(&at[((mh*2+mi)*16 + cl)*264 + 32*s + 8*q]);
      #pragma unroll
      for (int ni = 0; ni < 2; ++ni){
        int nn = n0 + (nh*2+ni)*16 + cl;
        b[ni] = *(const f16x8*)(&Bp[((size_t)((kb>>3) + 4*s + q)*N + nn)*8]);
      }
      #pragma unroll
      for (int mi = 0; mi < 2; ++mi)
        #pragma unroll
        for (int ni = 0; ni < 2; ++ni)
          acc[mi][ni] = __builtin_amdgcn_mfma_f32_16x16x32_f16(a[mi], b[ni], acc[mi][ni], 0,0,0);
    }
  }
  #pragma unroll
  for (int ni = 0; ni < 2; ++ni){
    int nn = n0 + (nh*2+ni)*16 + cl;
    float bv = bias[nn];
    #pragma unroll
    for (int mi = 0; mi < 2; ++mi)
      #pragma unroll
      for (int r = 0; r < 4; ++r){
        int mg = m0 + (mh*2+mi)*16 + q*4 + r;
        float v = acc[mi][ni][r] + bv;
        if (RELU) v = v > 0.f ? v : 0.f;
        if (OUTH) ((f16*)out)[(size_t)mg*N + nn] = (f16)v;
        else      ((float*)out)[(size_t)mg*N + nn] = v;
      }
  }
}

// ---------------- LSTM: 4 blocks x 8 envs, w_hh B-frags register-resident ----------------
__global__ __launch_bounds__(512) void lstm_k(const float* __restrict__ gx,
    const float* __restrict__ whh, const int* __restrict__ done,
    const float* __restrict__ h0, const float* __restrict__ c0, f16* __restrict__ hs){
  __shared__ float gates[8*512];
  __shared__ alignas(16) f16 hh[16*128];
  int e0 = blockIdx.x*8;
  int tid = threadIdx.x;
  int lane = tid & 63, w = tid >> 6;
  int q = lane >> 4, cl = lane & 15;
  f16x8 bfr[4][4];                                   // w_hh frags, live across all 128 steps
  #pragma unroll
  for (int nt = 0; nt < 4; ++nt){
    int n = w*64 + nt*16 + cl;
    #pragma unroll
    for (int s = 0; s < 4; ++s){
      f16x8 b;
      #pragma unroll
      for (int j = 0; j < 8; ++j) b[j] = (f16)whh[n*128 + 32*s + 8*q + j];
      bfr[nt][s] = b;
    }
  }
  float cc[2];
  #pragma unroll
  for (int u = 0; u < 2; ++u){
    int id = tid + u*512;                            // 1024 items = 8 envs x 128
    int b = id >> 7, j = id & 127;
    float m = 1.f - (float)done[e0 + b];             // done[t=0]
    cc[u] = c0[(e0+b)*128 + j] * m;
    hh[b*128 + j] = (f16)(h0[(e0+b)*128 + j] * m);
    hh[(8+b)*128 + j] = (f16)0.f;                    // zero pad rows 8..15
  }
  __syncthreads();
  for (int t = 0; t < 128; ++t){
    f32x4 acc[4] = {};
    f16x8 a[4];
    #pragma unroll
    for (int s = 0; s < 4; ++s)
      a[s] = *(const f16x8*)(&hh[cl*128 + 32*s + 8*q]);
    #pragma unroll
    for (int nt = 0; nt < 4; ++nt)
      #pragma unroll
      for (int s = 0; s < 4; ++s)
        acc[nt] = __builtin_amdgcn_mfma_f32_16x16x32_f16(a[s], bfr[nt][s], acc[nt], 0,0,0);
    #pragma unroll
    for (int nt = 0; nt < 4; ++nt)
      #pragma unroll
      for (int r = 0; r < 4; ++r){
        int e = q*4 + r;
        if (e < 8) gates[e*512 + w*64 + nt*16 + cl] = acc[nt][r];
      }
    __syncthreads();
    #pragma unroll
    for (int u = 0; u < 2; ++u){
      int id = tid + u*512;
      int b = id >> 7, j = id & 127;
      size_t rg = (size_t)t*32 + e0 + b;
      const float* gxr = gx + rg*512;
      float gi = gates[b*512 + j]       + gxr[j];
      float gf = gates[b*512 + 128 + j] + gxr[128 + j];
      float gg = gates[b*512 + 256 + j] + gxr[256 + j];
      float go = gates[b*512 + 384 + j] + gxr[384 + j];
      float c = sigf(gf)*cc[u] + sigf(gi)*tanhfast(gg);
      float h = sigf(go)*tanhfast(c);
      hs[rg*128 + j] = (f16)h;
      float m = 1.f;
      if (t < 127) m = 1.f - (float)done[(t+1)*32 + e0 + b];  // fuse next-step mask
      cc[u] = c*m;
      hh[b*128 + j] = (f16)(h*m);
    }
    __syncthreads();
  }
}

// ---------------- heads: (TB,128) @ [wa;wc]^T + bias -> out (TB,19) fp32 ----------------
__global__ __launch_bounds__(256) void heads_k(const f16* __restrict__ hs,
    const f16* __restrict__ Bp, const float* __restrict__ ba, const float* __restrict__ bc,
    float* __restrict__ out){
  __shared__ alignas(16) f16 at[64*128];
  int m0 = blockIdx.x*64;
  for (int i = threadIdx.x; i < 1024; i += 256)
    ((uint4*)at)[i] = ((const uint4*)(hs + (size_t)m0*128))[i];
  int lane = threadIdx.x & 63, w = threadIdx.x >> 6;
  int q = lane >> 4, cl = lane & 15;
  __syncthreads();
  f32x4 acc[2] = {};
  #pragma unroll
  for (int s = 0; s < 4; ++s){
    f16x8 a = *(const f16x8*)(&at[(w*16 + cl)*128 + 32*s + 8*q]);
    #pragma unroll
    for (int nt = 0; nt < 2; ++nt){
      f16x8 b = *(const f16x8*)(&Bp[((4*s + q)*32 + nt*16 + cl)*8]);
      acc[nt] = __builtin_amdgcn_mfma_f32_16x16x32_f16(a, b, acc[nt], 0,0,0);
    }
  }
  #pragma unroll
  for (int nt = 0; nt < 2; ++nt){
    int n = nt*16 + cl;
    if (n < 19){
      float bv = (n < 18) ? ba[n] : bc[0];
      #pragma unroll
      for (int r = 0; r < 4; ++r){
        int m = m0 + w*16 + q*4 + r;
        out[(size_t)m*19 + n] = acc[nt][r] + bv;
      }
    }
  }
}

extern "C" void kernel_launch(void* const* d_in, const int* in_sizes, int n_in,
                              void* d_out, int out_size, void* d_ws, size_t ws_size,
                              hipStream_t stream){
  const float* x   = (const float*)d_in[0];
  const int*   dn  = (const int*)d_in[1];
  const float* h0  = (const float*)d_in[2];
  const float* c0  = (const float*)d_in[3];
  const float* w1  = (const float*)d_in[4];
  const float* b1  = (const float*)d_in[5];
  const float* w2  = (const float*)d_in[6];
  const float* b2  = (const float*)d_in[7];
  const float* w3  = (const float*)d_in[8];
  const float* b3  = (const float*)d_in[9];
  const float* wf  = (const float*)d_in[10];
  const float* bf  = (const float*)d_in[11];
  const float* wih = (const float*)d_in[12];
  const float* whh = (const float*)d_in[13];
  const float* bih = (const float*)d_in[14];
  const float* bhh = (const float*)d_in[15];
  const float* wa  = (const float*)d_in[16];
  const float* ba  = (const float*)d_in[17];
  const float* wc  = (const float*)d_in[18];
  const float* bc  = (const float*)d_in[19];
  float* out = (float*)d_out;

  char* ws = (char*)d_ws;
  size_t off = 0;
  auto alloc = [&](size_t bytes)->char*{
    char* p = ws + off;
    off += (bytes + 255) & ~(size_t)255;
    return p;
  };
  f16*  y1   = (f16*)alloc(4096UL*400*32*2);   // 104.9 MB channels-last
  f16*  y2   = (f16*)alloc(4096UL*81*64*2);    // 42.5 MB
  f16*  y3   = (f16*)alloc(4096UL*3136*2);     // 25.7 MB
  f16*  feat = (f16*)alloc(4096UL*512*2);
  float* gx  = (float*)alloc(4096UL*512*4);
  f16*  hs   = (f16*)alloc(4096UL*128*2);
  f16*  Bp1  = (f16*)alloc(32UL*32*8*2);
  f16*  Bp2  = (f16*)alloc(64UL*64*8*2);
  f16*  Bp3  = (f16*)alloc(72UL*64*8*2);
  f16*  Bpf  = (f16*)alloc(392UL*512*8*2);
  f16*  Bpih = (f16*)alloc(64UL*512*8*2);
  f16*  Bph  = (f16*)alloc(16UL*32*8*2);
  float* bsum = (float*)alloc(512UL*4);

  prep_w1<<<32, 256, 0, stream>>>(w1, Bp1);
  prep_w2<<<128, 256, 0, stream>>>(w2, Bp2);
  prep_w3<<<144, 256, 0, stream>>>(w3, Bp3);
  prep_wf<<<6272, 256, 0, stream>>>(wf, Bpf);
  prep_wih<<<1024, 256, 0, stream>>>(wih, Bpih);
  prep_wheads<<<16, 256, 0, stream>>>(wa, wc, Bph);
  prep_bsum<<<2, 256, 0, stream>>>(bih, bhh, bsum);

  conv1_k<<<dim3(5, 4096), 128, 0, stream>>>(x, Bp1, b1, y1);
  conv2_k<<<dim3(2, 4096), 256, 0, stream>>>(y1, Bp2, b2, y2);
  conv3_k<<<4096, 256, 0, stream>>>(y2, Bp3, b3, y3);
  gemm_k<true,  true ><<<dim3(64, 8), 256, 0, stream>>>(y3,   Bpf,  bf,   (void*)feat, 4096, 512, 3136);
  gemm_k<false, false><<<dim3(64, 8), 256, 0, stream>>>(feat, Bpih, bsum, (void*)gx,   4096, 512, 512);
  lstm_k<<<4, 512, 0, stream>>>(gx, whh, dn, h0, c0, hs);
  heads_k<<<64, 256, 0, stream>>>(hs, Bph, ba, bc, out);
}

// Round 2
// 1105.764 us; speedup vs baseline: 1.1484x; 1.1484x over previous
//
#include <hip/hip_runtime.h>

typedef _Float16 f16;
typedef _Float16 f16x4 __attribute__((ext_vector_type(4)));
typedef _Float16 f16x8 __attribute__((ext_vector_type(8)));
typedef float f32x4 __attribute__((ext_vector_type(4)));

__device__ __forceinline__ float sigf(float x){ return 1.f/(1.f + __expf(-x)); }
__device__ __forceinline__ float tanhfast(float x){ return 2.f/(1.f + __expf(-2.f*x)) - 1.f; }

// ---------------- weight prep kernels (Bpack layout: [k>>3][n][k&7]) ----------------
// conv1 K-order is now (c,ky,kx) so the activation tile can stay channel-planar.
__global__ void prep_w1(const float* __restrict__ w, f16* __restrict__ dst){
  int idx = blockIdx.x*256 + threadIdx.x;            // 32*4*8*8 = 8192
  if (idx >= 8192) return;
  int och = idx >> 8, rem = idx & 255;
  int c = rem >> 6, ky = (rem >> 3) & 7, kx = rem & 7;
  int k = c*64 + ky*8 + kx;                           // K-order (c,ky,kx), K=256
  dst[(k>>3)*256 + och*8 + (k&7)] = (f16)(w[idx] * (1.f/255.f));  // fold x/255
}
__global__ void prep_w2(const float* __restrict__ w, f16* __restrict__ dst){
  int idx = blockIdx.x*256 + threadIdx.x;            // 64*32*4*4 = 32768
  if (idx >= 32768) return;
  int och = idx >> 9;
  int c = (idx >> 4) & 31, ky = (idx >> 2) & 3, kx = idx & 3;
  int k = (ky*4 + kx)*32 + c;                         // K=512
  dst[(k>>3)*512 + och*8 + (k&7)] = (f16)w[idx];
}
__global__ void prep_w3(const float* __restrict__ w, f16* __restrict__ dst){
  int idx = blockIdx.x*256 + threadIdx.x;            // 64*64*3*3 = 36864
  if (idx >= 36864) return;
  int och = idx / 576, r = idx % 576;
  int c = r / 9, r2 = r % 9;
  int ky = r2 / 3, kx = r2 % 3;
  int k = (ky*3 + kx)*64 + c;                         // K=576
  dst[(k>>3)*512 + och*8 + (k&7)] = (f16)w[idx];
}
// dst-indexed: coalesced 2B writes (128B/wave), gathered reads absorbed by L2
__global__ void prep_wf(const float* __restrict__ w, f16* __restrict__ dst){
  int idx = blockIdx.x*256 + threadIdx.x;            // 392*512*8 = 1605632
  if (idx >= 392*512*8) return;
  int j = idx & 7, n = (idx >> 3) & 511, k8 = idx >> 12;
  int kf = k8*8 + j;
  int c = kf & 63, p = kf >> 6;                      // p = iy*7+ix (0..48)
  dst[idx] = (f16)w[(size_t)n*3136 + c*49 + p];
}
__global__ void prep_wih(const float* __restrict__ w, f16* __restrict__ dst){
  int idx = blockIdx.x*256 + threadIdx.x;            // 64*512*8 = 262144
  if (idx >= 262144) return;
  int j = idx & 7, n = (idx >> 3) & 511, k8 = idx >> 12;
  dst[idx] = (f16)w[n*512 + k8*8 + j];               // fully coalesced r+w
}
__global__ void prep_wheads(const float* __restrict__ wa, const float* __restrict__ wc,
                            f16* __restrict__ dst){
  int idx = blockIdx.x*256 + threadIdx.x;            // 32*128 (pad N 19->32)
  if (idx >= 4096) return;
  int n = idx >> 7, k = idx & 127;
  float v = 0.f;
  if (n < 18) v = wa[n*128 + k];
  else if (n == 18) v = wc[k];
  dst[(k>>3)*256 + n*8 + (k&7)] = (f16)v;
}
__global__ void prep_bsum(const float* __restrict__ a, const float* __restrict__ b,
                          float* __restrict__ s){
  int i = blockIdx.x*256 + threadIdx.x;
  if (i < 512) s[i] = a[i] + b[i];
}

// ---------------- conv1: (TB,4,84,84) -> (TB,20,20,32) channels-last fp16 ----------------
// channel-planar tile [c][iy][ix]; staging = float4 load -> f16x4 ds_write_b64.
__global__ __launch_bounds__(128) void conv1_k(const float* __restrict__ x,
    const f16* __restrict__ Bp, const float* __restrict__ b1, f16* __restrict__ y1){
  __shared__ alignas(16) f16 tile[4*20*84];          // 13.4 KB
  int n = blockIdx.y, by = blockIdx.x;               // by in [0,5)
  int iy0 = by*16;
  for (int i = threadIdx.x; i < 1680; i += 128){
    int c = i / 420, r = i % 420;
    int iy = r / 21, x4 = r % 21;
    const float4* xp = (const float4*)(x + (((size_t)n*4 + c)*84 + iy0 + iy)*84) + x4;
    float4 v = *xp;
    f16x4 hv = { (f16)v.x, (f16)v.y, (f16)v.z, (f16)v.w };
    *(f16x4*)(&tile[(c*20 + iy)*84 + x4*4]) = hv;
  }
  int lane = threadIdx.x & 63, w = threadIdx.x >> 6;
  int q = lane >> 4, m = lane & 15;
  int och = w*16 + m;
  f16x8 bfr[8];
  #pragma unroll
  for (int s = 0; s < 8; ++s)
    bfr[s] = *(const f16x8*)(Bp + ((4*s + q)*32 + och)*8);
  __syncthreads();
  f32x4 acc[5] = {};
  #pragma unroll
  for (int mt = 0; mt < 5; ++mt){
    int px = mt*16 + m;
    int oy = px / 20, ox = px % 20;
    #pragma unroll
    for (int s = 0; s < 8; ++s){
      int k8 = 4*s + q;
      int c = k8 >> 3, ky = k8 & 7;                  // K-order (c,ky,kx)
      const f16* ap = &tile[(c*20 + oy*4 + ky)*84 + ox*4];
      f16x4 lo = *(const f16x4*)ap;
      f16x4 hi = *(const f16x4*)(ap + 4);
      f16x8 a = __builtin_shufflevector(lo, hi, 0,1,2,3,4,5,6,7);
      acc[mt] = __builtin_amdgcn_mfma_f32_16x16x32_f16(a, bfr[s], acc[mt], 0, 0, 0);
    }
  }
  float bias = b1[och];
  size_t obase = (size_t)n*400 + by*80;
  #pragma unroll
  for (int mt = 0; mt < 5; ++mt)
    #pragma unroll
    for (int r = 0; r < 4; ++r){
      int px = mt*16 + q*4 + r;
      float v = acc[mt][r] + bias; v = v > 0.f ? v : 0.f;
      y1[(obase + px)*32 + och] = (f16)v;
    }
}

// ---------------- conv2: (TB,20,20,32) -> (TB,9,9,64), K=512 ----------------
__global__ __launch_bounds__(256) void conv2_k(const f16* __restrict__ y1,
    const f16* __restrict__ Bp, const float* __restrict__ b2, f16* __restrict__ y2){
  __shared__ alignas(16) f16 tile[400*32];           // full y1 frame 25.6 KB
  int n = blockIdx.y, half = blockIdx.x;
  const f16* y1n = y1 + (size_t)n*12800;
  for (int i = threadIdx.x; i < 1600; i += 256)
    ((uint4*)tile)[i] = ((const uint4*)y1n)[i];
  int lane = threadIdx.x & 63, w = threadIdx.x >> 6;
  int q = lane >> 4, m = lane & 15;
  int mg = w >> 1, nt = w & 1;
  int och = half*32 + nt*16 + m;
  f16x8 bfr[16];
  #pragma unroll
  for (int s = 0; s < 16; ++s)
    bfr[s] = *(const f16x8*)(Bp + ((size_t)(4*s + q)*64 + och)*8);
  int basev[3];
  #pragma unroll
  for (int i = 0; i < 3; ++i){
    int px = (mg*3 + i)*16 + m;
    if (px > 80) px = 80;                            // pad rows clamp (stores guarded)
    int oy = px/9, ox = px%9;
    basev[i] = (oy*2)*20 + ox*2;
  }
  __syncthreads();
  f32x4 acc[3] = {};
  #pragma unroll
  for (int s = 0; s < 16; ++s){
    int k8 = 4*s + q;
    int c0 = (k8 & 3)*8;
    int kk = k8 >> 2;
    int off = ((kk >> 2)*20 + (kk & 3))*32 + c0;     // (ky*20+kx)*32+c0
    #pragma unroll
    for (int i = 0; i < 3; ++i){
      f16x8 a = *(const f16x8*)(&tile[basev[i]*32 + off]);
      acc[i] = __builtin_amdgcn_mfma_f32_16x16x32_f16(a, bfr[s], acc[i], 0, 0, 0);
    }
  }
  float bias = b2[och];
  #pragma unroll
  for (int i = 0; i < 3; ++i)
    #pragma unroll
    for (int r = 0; r < 4; ++r){
      int px = (mg*3 + i)*16 + q*4 + r;
      if (px < 81){
        float v = acc[i][r] + bias; v = v > 0.f ? v : 0.f;
        y2[((size_t)n*81 + px)*64 + och] = (f16)v;
      }
    }
}

// ---------------- conv3: (TB,9,9,64) -> (TB,49*64) flat channels-last, K=576 ----------------
__global__ __launch_bounds__(256) void conv3_k(const f16* __restrict__ y2,
    const f16* __restrict__ Bp, const float* __restrict__ b3, f16* __restrict__ y3){
  __shared__ alignas(16) f16 tile[81*64];            // 10.4 KB
  int n = blockIdx.x;
  const f16* y2n = y2 + (size_t)n*5184;
  for (int i = threadIdx.x; i < 648; i += 256)
    ((uint4*)tile)[i] = ((const uint4*)y2n)[i];
  int lane = threadIdx.x & 63, w = threadIdx.x >> 6;
  int q = lane >> 4, m = lane & 15;
  int och = w*16 + m;
  int basev[4];
  #pragma unroll
  for (int i = 0; i < 4; ++i){
    int px = i*16 + m; if (px > 48) px = 48;
    basev[i] = (px/7)*9 + (px%7);
  }
  __syncthreads();
  f32x4 acc[4] = {};
  for (int s = 0; s < 18; ++s){
    int k8 = 4*s + q;
    int c0 = (k8 & 7)*8;
    int kxy = k8 >> 3;                               // 0..8
    int ky = kxy/3, kx = kxy%3;
    f16x8 b = *(const f16x8*)(Bp + ((size_t)k8*64 + och)*8);
    int off = (ky*9 + kx)*64 + c0;
    #pragma unroll
    for (int i = 0; i < 4; ++i){
      f16x8 a = *(const f16x8*)(&tile[basev[i]*64 + off]);
      acc[i] = __builtin_amdgcn_mfma_f32_16x16x32_f16(a, b, acc[i], 0, 0, 0);
    }
  }
  float bias = b3[och];
  #pragma unroll
  for (int i = 0; i < 4; ++i)
    #pragma unroll
    for (int r = 0; r < 4; ++r){
      int px = i*16 + q*4 + r;
      if (px < 49){
        float v = acc[i][r] + bias; v = v > 0.f ? v : 0.f;
        y3[((size_t)n*49 + px)*64 + och] = (f16)v;
      }
    }
}

// ---------------- generic GEMM: out(M,N) = A(M,K)fp16 @ Bpack + bias ----------------
template<bool RELU, bool OUTH>
__global__ __launch_bounds__(256) void gemm_k(const f16* __restrict__ A,
    const f16* __restrict__ Bp, const float* __restrict__ bias, void* __restrict__ out,
    int M, int N, int K){
  __shared__ alignas(16) f16 at[64*264];             // 64 rows, K_BLK=256 (+8 pad)
  int m0 = blockIdx.x*64, n0 = blockIdx.y*64;
  int lane = threadIdx.x & 63, w = threadIdx.x >> 6;
  int q = lane >> 4, cl = lane & 15;
  int mh = w >> 1, nh = w & 1;
  f32x4 acc[2][2] = {};
  for (int kb = 0; kb < K; kb += 256){
    int kblen = K - kb; if (kblen > 256) kblen = 256;
    int c8n = kblen >> 3;
    __syncthreads();
    int tot = 64*c8n;
    for (int i = threadIdx.x; i < tot; i += 256){
      int row, c8;
      if (c8n == 32){ row = i >> 5; c8 = i & 31; } else { row = i >> 3; c8 = i & 7; }
      *(f16x8*)(&at[row*264 + c8*8]) = *(const f16x8*)(&A[(size_t)(m0+row)*K + kb + c8*8]);
    }
    __syncthreads();
    int nks = kblen >> 5;
    for (int s = 0; s < nks; ++s){
      f16x8 a[2], b[2];
      #pragma unroll
      for (int mi = 0; mi < 2; ++mi)
        a[mi] = *(const f16x8*)(&at[((mh*2+mi)*16 + cl)*264 + 32*s + 8*q]);
      #pragma unroll
      for (int ni = 0; ni < 2; ++ni){
        int nn = n0 + (nh*2+ni)*16 + cl;
        b[ni] = *(const f16x8*)(&Bp[((size_t)((kb>>3) + 4*s + q)*N + nn)*8]);
      }
      #pragma unroll
      for (int mi = 0; mi < 2; ++mi)
        #pragma unroll
        for (int ni = 0; ni < 2; ++ni)
          acc[mi][ni] = __builtin_amdgcn_mfma_f32_16x16x32_f16(a[mi], b[ni], acc[mi][ni], 0,0,0);
    }
  }
  #pragma unroll
  for (int ni = 0; ni < 2; ++ni){
    int nn = n0 + (nh*2+ni)*16 + cl;
    float bv = bias[nn];
    #pragma unroll
    for (int mi = 0; mi < 2; ++mi)
      #pragma unroll
      for (int r = 0; r < 4; ++r){
        int mg = m0 + (mh*2+mi)*16 + q*4 + r;
        float v = acc[mi][ni][r] + bv;
        if (RELU) v = v > 0.f ? v : 0.f;
        if (OUTH) ((f16*)out)[(size_t)mg*N + nn] = (f16)v;
        else      ((float*)out)[(size_t)mg*N + nn] = v;
      }
  }
}

// ---------------- LSTM: 4 blocks x 8 envs, w_hh B-frags register-resident ----------------
__global__ __launch_bounds__(512) void lstm_k(const float* __restrict__ gx,
    const float* __restrict__ whh, const int* __restrict__ done,
    const float* __restrict__ h0, const float* __restrict__ c0, f16* __restrict__ hs){
  __shared__ float gates[8*512];
  __shared__ alignas(16) f16 hh[16*128];
  int e0 = blockIdx.x*8;
  int tid = threadIdx.x;
  int lane = tid & 63, w = tid >> 6;
  int q = lane >> 4, cl = lane & 15;
  f16x8 bfr[4][4];                                   // w_hh frags, live across all 128 steps
  #pragma unroll
  for (int nt = 0; nt < 4; ++nt){
    int n = w*64 + nt*16 + cl;
    #pragma unroll
    for (int s = 0; s < 4; ++s){
      f16x8 b;
      #pragma unroll
      for (int j = 0; j < 8; ++j) b[j] = (f16)whh[n*128 + 32*s + 8*q + j];
      bfr[nt][s] = b;
    }
  }
  float cc[2];
  #pragma unroll
  for (int u = 0; u < 2; ++u){
    int id = tid + u*512;                            // 1024 items = 8 envs x 128
    int b = id >> 7, j = id & 127;
    float m = 1.f - (float)done[e0 + b];             // done[t=0]
    cc[u] = c0[(e0+b)*128 + j] * m;
    hh[b*128 + j] = (f16)(h0[(e0+b)*128 + j] * m);
    hh[(8+b)*128 + j] = (f16)0.f;                    // zero pad rows 8..15
  }
  __syncthreads();
  for (int t = 0; t < 128; ++t){
    // prefetch gx for this step into regs: latency hides behind MFMA + barrier
    float gpre[2][4];
    #pragma unroll
    for (int u = 0; u < 2; ++u){
      int id = tid + u*512;
      int b = id >> 7, j = id & 127;
      const float* gxr = gx + ((size_t)t*32 + e0 + b)*512;
      gpre[u][0] = gxr[j];       gpre[u][1] = gxr[128 + j];
      gpre[u][2] = gxr[256 + j]; gpre[u][3] = gxr[384 + j];
    }
    f32x4 acc[4] = {};
    f16x8 a[4];
    #pragma unroll
    for (int s = 0; s < 4; ++s)
      a[s] = *(const f16x8*)(&hh[cl*128 + 32*s + 8*q]);
    #pragma unroll
    for (int nt = 0; nt < 4; ++nt)
      #pragma unroll
      for (int s = 0; s < 4; ++s)
        acc[nt] = __builtin_amdgcn_mfma_f32_16x16x32_f16(a[s], bfr[nt][s], acc[nt], 0,0,0);
    #pragma unroll
    for (int nt = 0; nt < 4; ++nt)
      #pragma unroll
      for (int r = 0; r < 4; ++r){
        int e = q*4 + r;
        if (e < 8) gates[e*512 + w*64 + nt*16 + cl] = acc[nt][r];
      }
    __syncthreads();
    #pragma unroll
    for (int u = 0; u < 2; ++u){
      int id = tid + u*512;
      int b = id >> 7, j = id & 127;
      size_t rg = (size_t)t*32 + e0 + b;
      float gi = gates[b*512 + j]       + gpre[u][0];
      float gf = gates[b*512 + 128 + j] + gpre[u][1];
      float gg = gates[b*512 + 256 + j] + gpre[u][2];
      float go = gates[b*512 + 384 + j] + gpre[u][3];
      float c = sigf(gf)*cc[u] + sigf(gi)*tanhfast(gg);
      float h = sigf(go)*tanhfast(c);
      hs[rg*128 + j] = (f16)h;
      float m = 1.f;
      if (t < 127) m = 1.f - (float)done[(t+1)*32 + e0 + b];  // fuse next-step mask
      cc[u] = c*m;
      hh[b*128 + j] = (f16)(h*m);
    }
    __syncthreads();
  }
}

// ---------------- heads: (TB,128) @ [wa;wc]^T + bias -> out (TB,19) fp32 ----------------
__global__ __launch_bounds__(256) void heads_k(const f16* __restrict__ hs,
    const f16* __restrict__ Bp, const float* __restrict__ ba, const float* __restrict__ bc,
    float* __restrict__ out){
  __shared__ alignas(16) f16 at[64*128];
  int m0 = blockIdx.x*64;
  for (int i = threadIdx.x; i < 1024; i += 256)
    ((uint4*)at)[i] = ((const uint4*)(hs + (size_t)m0*128))[i];
  int lane = threadIdx.x & 63, w = threadIdx.x >> 6;
  int q = lane >> 4, cl = lane & 15;
  __syncthreads();
  f32x4 acc[2] = {};
  #pragma unroll
  for (int s = 0; s < 4; ++s){
    f16x8 a = *(const f16x8*)(&at[(w*16 + cl)*128 + 32*s + 8*q]);
    #pragma unroll
    for (int nt = 0; nt < 2; ++nt){
      f16x8 b = *(const f16x8*)(&Bp[((4*s + q)*32 + nt*16 + cl)*8]);
      acc[nt] = __builtin_amdgcn_mfma_f32_16x16x32_f16(a, b, acc[nt], 0,0,0);
    }
  }
  #pragma unroll
  for (int nt = 0; nt < 2; ++nt){
    int n = nt*16 + cl;
    if (n < 19){
      float bv = (n < 18) ? ba[n] : bc[0];
      #pragma unroll
      for (int r = 0; r < 4; ++r){
        int m = m0 + w*16 + q*4 + r;
        out[(size_t)m*19 + n] = acc[nt][r] + bv;
      }
    }
  }
}

extern "C" void kernel_launch(void* const* d_in, const int* in_sizes, int n_in,
                              void* d_out, int out_size, void* d_ws, size_t ws_size,
                              hipStream_t stream){
  const float* x   = (const float*)d_in[0];
  const int*   dn  = (const int*)d_in[1];
  const float* h0  = (const float*)d_in[2];
  const float* c0  = (const float*)d_in[3];
  const float* w1  = (const float*)d_in[4];
  const float* b1  = (const float*)d_in[5];
  const float* w2  = (const float*)d_in[6];
  const float* b2  = (const float*)d_in[7];
  const float* w3  = (const float*)d_in[8];
  const float* b3  = (const float*)d_in[9];
  const float* wf  = (const float*)d_in[10];
  const float* bf  = (const float*)d_in[11];
  const float* wih = (const float*)d_in[12];
  const float* whh = (const float*)d_in[13];
  const float* bih = (const float*)d_in[14];
  const float* bhh = (const float*)d_in[15];
  const float* wa  = (const float*)d_in[16];
  const float* ba  = (const float*)d_in[17];
  const float* wc  = (const float*)d_in[18];
  const float* bc  = (const float*)d_in[19];
  float* out = (float*)d_out;

  char* ws = (char*)d_ws;
  size_t off = 0;
  auto alloc = [&](size_t bytes)->char*{
    char* p = ws + off;
    off += (bytes + 255) & ~(size_t)255;
    return p;
  };
  f16*  y1   = (f16*)alloc(4096UL*400*32*2);   // 104.9 MB channels-last
  f16*  y2   = (f16*)alloc(4096UL*81*64*2);    // 42.5 MB
  f16*  y3   = (f16*)alloc(4096UL*3136*2);     // 25.7 MB
  f16*  feat = (f16*)alloc(4096UL*512*2);
  float* gx  = (float*)alloc(4096UL*512*4);
  f16*  hs   = (f16*)alloc(4096UL*128*2);
  f16*  Bp1  = (f16*)alloc(32UL*32*8*2);
  f16*  Bp2  = (f16*)alloc(64UL*64*8*2);
  f16*  Bp3  = (f16*)alloc(72UL*64*8*2);
  f16*  Bpf  = (f16*)alloc(392UL*512*8*2);
  f16*  Bpih = (f16*)alloc(64UL*512*8*2);
  f16*  Bph  = (f16*)alloc(16UL*32*8*2);
  float* bsum = (float*)alloc(512UL*4);

  prep_w1<<<32, 256, 0, stream>>>(w1, Bp1);
  prep_w2<<<128, 256, 0, stream>>>(w2, Bp2);
  prep_w3<<<144, 256, 0, stream>>>(w3, Bp3);
  prep_wf<<<6272, 256, 0, stream>>>(wf, Bpf);
  prep_wih<<<1024, 256, 0, stream>>>(wih, Bpih);
  prep_wheads<<<16, 256, 0, stream>>>(wa, wc, Bph);
  prep_bsum<<<2, 256, 0, stream>>>(bih, bhh, bsum);

  conv1_k<<<dim3(5, 4096), 128, 0, stream>>>(x, Bp1, b1, y1);
  conv2_k<<<dim3(2, 4096), 256, 0, stream>>>(y1, Bp2, b2, y2);
  conv3_k<<<4096, 256, 0, stream>>>(y2, Bp3, b3, y3);
  gemm_k<true,  true ><<<dim3(64, 8), 256, 0, stream>>>(y3,   Bpf,  bf,   (void*)feat, 4096, 512, 3136);
  gemm_k<false, false><<<dim3(64, 8), 256, 0, stream>>>(feat, Bpih, bsum, (void*)gx,   4096, 512, 512);
  lstm_k<<<4, 512, 0, stream>>>(gx, whh, dn, h0, c0, hs);
  heads_k<<<64, 256, 0, stream>>>(hs, Bph, ba, bc, out);
}